// Round 8
// baseline (21387.488 us; speedup 1.0000x reference)
//
#include <hip/hip_runtime.h>
#include <hip/hip_bf16.h>

#define HH 256
#define SSL 512

using short8 = __attribute__((ext_vector_type(8))) short;
using f32x4  = __attribute__((ext_vector_type(4))) float;

__device__ __forceinline__ unsigned short f2bf(float f) {
  unsigned int u = __float_as_uint(f);
  u += 0x7FFFu + ((u >> 16) & 1u);
  return (unsigned short)(u >> 16);
}
// lgkm drain + raw barrier + sched pin; vmcnt NOT drained (global loads stay in flight)
__device__ __forceinline__ void sync_lds() {
  asm volatile("s_waitcnt lgkmcnt(0)" ::: "memory");
  __builtin_amdgcn_s_barrier();
  __builtin_amdgcn_sched_barrier(0);
}

// ---------------------------------------------------------------------------
// Prep (R12): BOTH W_ih and W_hh -> bf16 MFMA-fragment images with the same
// indexing: F(p,g,w,kt) = ((p*3+g)*4+w)*8+kt; row = g*256 + p*64 + w*16 +
// (l&15); k0 = kt*32 + (l>>4)*8. blocks 0..95 -> Wih, 96..191 -> Whh.
// Block 0 additionally zeroes the exchange flags (replaces hipMemsetAsync:
// graph-capture-safe, and ordered before gru_scan by same-stream dispatch).
// ---------------------------------------------------------------------------
__global__ __launch_bounds__(256) void prep_pack(
    const float* __restrict__ Wih, const float* __restrict__ Whh,
    unsigned short* __restrict__ wih_frag, unsigned short* __restrict__ whh_frag,
    int* __restrict__ flags)
{
  int blk = blockIdx.x;
  if (blk == 0) {
#pragma unroll
    for (int i = 0; i < 8; i++) flags[threadIdx.x * 8 + i] = 0;
  }
  const float* srcW = (blk < 96) ? Wih : Whh;
  unsigned short* dst = (blk < 96) ? wih_frag : whh_frag;
  int gid = (blk % 96) * 256 + threadIdx.x;  // 0..24575
  int f = gid >> 6, l = gid & 63;            // f = 0..383
  int kt = f & 7, w = (f >> 3) & 3, g = (f >> 5) % 3, p = f / 96;
  int row = g * HH + p * 64 + w * 16 + (l & 15);
  int k0  = kt * 32 + (l >> 4) * 8;
  const float* src = srcW + (size_t)row * HH + k0;
  unsigned int o[4];
#pragma unroll
  for (int i = 0; i < 4; i++)
    o[i] = (unsigned int)f2bf(src[2 * i]) | ((unsigned int)f2bf(src[2 * i + 1]) << 16);
  *(uint4*)(dst + ((size_t)f * 64 + l) * 8) = *(uint4*)o;
}

// ---------------------------------------------------------------------------
// Fused split GRU scan (R12 = R11 logic, regular launch). 256 blocks x 256
// thr; co-residency BY CONSTRUCTION: grid == 256 CUs, LDS 82176B > 80KB =>
// 1 block/CU, __launch_bounds__(256,1). (R11 post-mortem: cooperative launch
// failed => kernel never ran => out==0 => absmax 0.906 == max|h_ref|.)
// Block (bg = blockIdx&63, p = blockIdx>>6): batch group bg (4 rows), h-dim
// part p (64 dims); parts of one bg land on one XCD (blockIdx%8 == bg%8).
// Per wave: 24 gi-MFMAs (Wih x X col, X read once: 134MB) + 24 gh-MFMAs
// (Whh x h) -- the 247us standalone gi GEMM is GONE. Gates in-register.
// h-exchange per step: 512B/block via agent-scope atomics (LLC) + monotonic
// flags (ACQUIRE poll), parity double-buffered hx; LLC load latency hides
// under the gi-MFMA block.
// ---------------------------------------------------------------------------
__global__ __launch_bounds__(256, 1) void gru_scan(
    const float* __restrict__ tree, const float* __restrict__ seq,
    const int* __restrict__ mask,
    const unsigned short* __restrict__ wihf, const unsigned short* __restrict__ whhf,
    const float* __restrict__ bih, const float* __restrict__ bhh,
    unsigned short* __restrict__ hx, int* __restrict__ flags,
    float* __restrict__ out)
{
  // LDS: hbuf 2x1088 shorts (4352B) + xbuf 2x1088 (4352B) + lsum; padded
  // >80KB to force 1 block/CU.
  __shared__ __align__(16) unsigned char lds[82176];
  unsigned short (*hbuf)[1088] = (unsigned short(*)[1088])lds;
  unsigned short (*xbuf)[1088] = (unsigned short(*)[1088])(lds + 4352);
  int* lsum = (int*)(lds + 8704);

  const int tid  = threadIdx.x;
  const int lane = tid & 63;
  const int w    = tid >> 6;          // wave = 16-dim tile within the part
  const int n16  = lane & 15;
  const int quad = lane >> 4;
  const int b    = n16 & 3;           // batch row owned by this lane
  const int rep  = n16 >> 2;          // replica (4 lanes duplicate work)
  const int p    = blockIdx.x >> 6;   // part: h-dims [p*64, p*64+64)
  const int bg   = blockIdx.x & 63;   // batch group
  const int brow0 = bg * 4;
  const int jbase = p * 64 + w * 16 + quad * 4;   // 4 owned h-dims

  if (tid < 4) lsum[tid] = 0;

  // lane-resident h (f32)
  f32x4 h4 = *(const f32x4*)(tree + (size_t)(brow0 + b) * HH + jbase);

  // stage FULL initial h into hbuf[0]: thread -> (batch tid>>6, dims (tid&63)*4)
  {
    int bi = tid >> 6, d0 = (tid & 63) * 4;
    f32x4 tv = *(const f32x4*)(tree + (size_t)(brow0 + bi) * HH + d0);
    unsigned int lo = (unsigned)f2bf(tv[0]) | ((unsigned)f2bf(tv[1]) << 16);
    unsigned int hi = (unsigned)f2bf(tv[2]) | ((unsigned)f2bf(tv[3]) << 16);
    int kt = d0 >> 5, q = (d0 >> 3) & 3;
    *(unsigned long long*)&hbuf[0][(kt * 17 + bi * 4 + q) * 8 + (d0 & 7)] =
        (unsigned long long)lo | ((unsigned long long)hi << 32);
  }
  // X staging pointers: same (bi,d0) chunk; stage X(0); preload X(1) to regs
  const float* xgp = seq + ((size_t)(brow0 + (tid >> 6)) * HH + (tid & 63) * 4) * SSL;
  float xv0, xv1, xv2, xv3;
  {
    int bi = tid >> 6, d0 = (tid & 63) * 4;
    float a0 = xgp[0 * SSL], a1 = xgp[1 * SSL], a2 = xgp[2 * SSL], a3 = xgp[3 * SSL];
    unsigned int lo = (unsigned)f2bf(a0) | ((unsigned)f2bf(a1) << 16);
    unsigned int hi = (unsigned)f2bf(a2) | ((unsigned)f2bf(a3) << 16);
    int kt = d0 >> 5, q = (d0 >> 3) & 3;
    *(unsigned long long*)&xbuf[0][(kt * 17 + bi * 4 + q) * 8 + (d0 & 7)] =
        (unsigned long long)lo | ((unsigned long long)hi << 32);
    xv0 = xgp[0 * SSL + 1]; xv1 = xgp[1 * SSL + 1];
    xv2 = xgp[2 * SSL + 1]; xv3 = xgp[3 * SSL + 1];
  }
  {
    const int* mp = mask + (size_t)(brow0 + w) * SSL + lane * 8;
    int4 a = *(const int4*)mp;
    int4 c = *(const int4*)(mp + 4);
    atomicAdd(&lsum[w], a.x + a.y + a.z + a.w + c.x + c.y + c.z + c.w);
  }

  // W fragments: 3 gates x 8 kt each for Wih (VGPR) and Whh (AGPR)
  short8 awI[3][8], awH[3][8];
#pragma unroll
  for (int g = 0; g < 3; g++)
#pragma unroll
    for (int kt = 0; kt < 8; kt++) {
      size_t F = (size_t)(((p * 3 + g) * 4 + w) * 8 + kt) * 512;
      awI[g][kt] = *(const short8*)(wihf + F + (size_t)lane * 8);
      awH[g][kt] = *(const short8*)(whhf + F + (size_t)lane * 8);
    }
  // Pin (R5 lesson: without pins the allocator re-loads W from L2 every step)
#pragma unroll
  for (int g = 0; g < 3; g++)
#pragma unroll
    for (int kt = 0; kt < 8; kt++) {
      asm volatile("" : "+v"(awI[g][kt]));
      asm volatile("" : "+a"(awH[g][kt]));
    }

  // biases (f32, lane-resident): r/z combined, n split (torch GRUCell math)
  f32x4 brz = *(const f32x4*)(bih + jbase);
  f32x4 bzz = *(const f32x4*)(bih + HH + jbase);
  f32x4 bin = *(const f32x4*)(bih + 2 * HH + jbase);
  f32x4 bhn = *(const f32x4*)(bhh + 2 * HH + jbase);
  {
    f32x4 t0 = *(const f32x4*)(bhh + jbase);
    f32x4 t1 = *(const f32x4*)(bhh + HH + jbase);
#pragma unroll
    for (int e = 0; e < 4; e++) { brz[e] += t0[e]; bzz[e] += t1[e]; }
  }

  __syncthreads();
  int mylast = lsum[b] - 1; if (mylast < 0) mylast = 0;

  for (int t = 0; t < SSL; t++) {
    const int cb = t & 1, nb = cb ^ 1;

    // ---- xb fragments (X(t), staged last step) ----
    short8 xb[8];
    const unsigned short* xrp = &xbuf[cb][0] + (b * 4 + quad) * 8;
#pragma unroll
    for (int kt = 0; kt < 8; kt++)
      xb[kt] = *(const short8*)(xrp + kt * 136);

    // ---- poll partners for h_{t-1} (ACQUIRE); issue hx loads (hidden under gi-MFMA) ----
    unsigned long long hv0 = 0, hv1 = 0;
    if (t > 0) {
      const int* fl = flags + bg * 32;
      while (true) {
        int f0 = __hip_atomic_load(fl + 0, __ATOMIC_ACQUIRE, __HIP_MEMORY_SCOPE_AGENT);
        int f1 = __hip_atomic_load(fl + 1, __ATOMIC_ACQUIRE, __HIP_MEMORY_SCOPE_AGENT);
        int f2 = __hip_atomic_load(fl + 2, __ATOMIC_ACQUIRE, __HIP_MEMORY_SCOPE_AGENT);
        int f3 = __hip_atomic_load(fl + 3, __ATOMIC_ACQUIRE, __HIP_MEMORY_SCOPE_AGENT);
        if (f0 >= t && f1 >= t && f2 >= t && f3 >= t) break;
      }
      if (tid < 128) {
        int q4 = tid >> 5, bi = (tid >> 3) & 3, ch = tid & 7;
        const unsigned long long* s = (const unsigned long long*)
            (hx + (((size_t)nb * 64 + bg) * 4 + bi) * 256 + q4 * 64 + ch * 8);
        hv0 = __hip_atomic_load(s,     __ATOMIC_RELAXED, __HIP_MEMORY_SCOPE_AGENT);
        hv1 = __hip_atomic_load(s + 1, __ATOMIC_RELAXED, __HIP_MEMORY_SCOPE_AGENT);
      }
    }

    // ---- gi-MFMAs: 3 chains x 8 (independent of the exchange) ----
    f32x4 ri = f32x4{0.f, 0.f, 0.f, 0.f}, zi = ri, ni = ri;
#pragma unroll
    for (int kt = 0; kt < 8; kt++) {
      ri = __builtin_amdgcn_mfma_f32_16x16x32_bf16(awI[0][kt], xb[kt], ri, 0, 0, 0);
      zi = __builtin_amdgcn_mfma_f32_16x16x32_bf16(awI[1][kt], xb[kt], zi, 0, 0, 0);
      ni = __builtin_amdgcn_mfma_f32_16x16x32_bf16(awI[2][kt], xb[kt], ni, 0, 0, 0);
    }

    // ---- stage hbuf[cb] with h_{t-1} (t=0 pre-staged at init) ----
    if (t > 0) {
      if (tid < 128) {
        int q4 = tid >> 5, bi = (tid >> 3) & 3, ch = tid & 7;
        int d = q4 * 64 + ch * 8;
        int kt = d >> 5, qq = (d >> 3) & 3;
        unsigned long long* dst = (unsigned long long*)&hbuf[cb][(kt * 17 + bi * 4 + qq) * 8];
        dst[0] = hv0; dst[1] = hv1;
      }
      sync_lds();
    }

    // ---- gh-MFMAs: 3 chains x 8 ----
    short8 hb[8];
    const unsigned short* hrp = &hbuf[cb][0] + (b * 4 + quad) * 8;
#pragma unroll
    for (int kt = 0; kt < 8; kt++)
      hb[kt] = *(const short8*)(hrp + kt * 136);
    f32x4 rh = f32x4{0.f, 0.f, 0.f, 0.f}, zh = rh, nh = rh;
#pragma unroll
    for (int kt = 0; kt < 8; kt++) {
      rh = __builtin_amdgcn_mfma_f32_16x16x32_bf16(awH[0][kt], hb[kt], rh, 0, 0, 0);
      zh = __builtin_amdgcn_mfma_f32_16x16x32_bf16(awH[1][kt], hb[kt], zh, 0, 0, 0);
      nh = __builtin_amdgcn_mfma_f32_16x16x32_bf16(awH[2][kt], hb[kt], nh, 0, 0, 0);
    }

    // ---- gates in-register (wave owns its tile: no select) ----
#pragma unroll
    for (int e = 0; e < 4; e++) {
      float r = __builtin_amdgcn_rcpf(1.f + __expf(-(ri[e] + rh[e] + brz[e])));
      float z = __builtin_amdgcn_rcpf(1.f + __expf(-(zi[e] + zh[e] + bzz[e])));
      float a = ni[e] + bin[e] + r * (nh[e] + bhn[e]);
      float nn = 1.f - 2.f * __builtin_amdgcn_rcpf(__expf(2.f * a) + 1.f);
      h4[e] = nn + z * (h4[e] - nn);
    }

    // ---- post own slice h_t -> hx[cb] (agent atomics => LLC-visible) ----
    if (rep == 0) {
      unsigned int lo = (unsigned)f2bf(h4[0]) | ((unsigned)f2bf(h4[1]) << 16);
      unsigned int hi = (unsigned)f2bf(h4[2]) | ((unsigned)f2bf(h4[3]) << 16);
      unsigned long long u = (unsigned long long)lo | ((unsigned long long)hi << 32);
      __hip_atomic_store((unsigned long long*)
          (hx + (((size_t)cb * 64 + bg) * 4 + b) * 256 + jbase),
          u, __ATOMIC_RELAXED, __HIP_MEMORY_SCOPE_AGENT);
    }
    if (t == mylast)
      *(f32x4*)(out + (size_t)(brow0 + b) * HH + jbase) = h4;

    // every wave drains its own stores, then block joins, then tid0 releases
    asm volatile("s_waitcnt vmcnt(0)" ::: "memory");
    __syncthreads();
    if (tid == 0)
      __hip_atomic_store(flags + bg * 32 + p, t + 1,
                         __ATOMIC_RELEASE, __HIP_MEMORY_SCOPE_AGENT);

    // ---- stage xbuf[nb] <- X(t+1) (regs), then prefetch X(t+2) ----
    {
      int bi = tid >> 6, d0 = (tid & 63) * 4;
      unsigned int lo = (unsigned)f2bf(xv0) | ((unsigned)f2bf(xv1) << 16);
      unsigned int hi = (unsigned)f2bf(xv2) | ((unsigned)f2bf(xv3) << 16);
      int kt = d0 >> 5, q = (d0 >> 3) & 3;
      *(unsigned long long*)&xbuf[nb][(kt * 17 + bi * 4 + q) * 8 + (d0 & 7)] =
          (unsigned long long)lo | ((unsigned long long)hi << 32);
      int tn = (t + 2 < SSL) ? t + 2 : SSL - 1;
      xv0 = xgp[0 * SSL + tn]; xv1 = xgp[1 * SSL + tn];
      xv2 = xgp[2 * SSL + tn]; xv3 = xgp[3 * SSL + tn];
    }
    sync_lds();
  }
}

extern "C" void kernel_launch(void* const* d_in, const int* in_sizes, int n_in,
                              void* d_out, int out_size, void* d_ws, size_t ws_size,
                              hipStream_t stream) {
  const float* tree = (const float*)d_in[0];
  const float* seq  = (const float*)d_in[1];
  const int*   mask = (const int*)d_in[2];
  const float* Wih  = (const float*)d_in[3];
  const float* Whh  = (const float*)d_in[4];
  const float* bih  = (const float*)d_in[5];
  const float* bhh  = (const float*)d_in[6];
  float* out = (float*)d_out;

  unsigned short* hx    = (unsigned short*)d_ws;                    // 262,144 B
  int*            flags = (int*)((char*)d_ws + 262144);             //   8,192 B
  unsigned short* wihf  = (unsigned short*)((char*)d_ws + 270336);  // 393,216 B
  unsigned short* whhf  = (unsigned short*)((char*)d_ws + 663552);  // 393,216 B

  prep_pack<<<192, 256, 0, stream>>>(Wih, Whh, wihf, whhf, flags);
  gru_scan<<<256, 256, 0, stream>>>(tree, seq, mask, wihf, whhf,
                                    bih, bhh, hx, flags, out);
}

// Round 9
// 2620.730 us; speedup vs baseline: 8.1609x; 8.1609x over previous
//
#include <hip/hip_runtime.h>
#include <hip/hip_bf16.h>

#define HH 256
#define SSL 512

using short8 = __attribute__((ext_vector_type(8))) short;
using f32x4  = __attribute__((ext_vector_type(4))) float;

__device__ __forceinline__ unsigned short f2bf(float f) {
  unsigned int u = __float_as_uint(f);
  u += 0x7FFFu + ((u >> 16) & 1u);
  return (unsigned short)(u >> 16);
}
// lgkm drain + raw barrier + sched pin; vmcnt NOT drained (global loads stay in flight)
__device__ __forceinline__ void sync_lds() {
  asm volatile("s_waitcnt lgkmcnt(0)" ::: "memory");
  __builtin_amdgcn_s_barrier();
  __builtin_amdgcn_sched_barrier(0);
}

// ---------------------------------------------------------------------------
// Prep (R13 = R12): W_ih / W_hh -> bf16 MFMA-fragment images,
// F(p,g,w,kt) = ((p*3+g)*4+w)*8+kt; row = g*256 + p*64 + w*16 + (l&15);
// k0 = kt*32 + (l>>4)*8. blocks 0..95 -> Wih, 96..191 -> Whh.
// Block 0 zeroes exchange flags (graph-capture-safe).
// ---------------------------------------------------------------------------
__global__ __launch_bounds__(256) void prep_pack(
    const float* __restrict__ Wih, const float* __restrict__ Whh,
    unsigned short* __restrict__ wih_frag, unsigned short* __restrict__ whh_frag,
    int* __restrict__ flags)
{
  int blk = blockIdx.x;
  if (blk == 0) {
#pragma unroll
    for (int i = 0; i < 8; i++) flags[threadIdx.x * 8 + i] = 0;
  }
  const float* srcW = (blk < 96) ? Wih : Whh;
  unsigned short* dst = (blk < 96) ? wih_frag : whh_frag;
  int gid = (blk % 96) * 256 + threadIdx.x;  // 0..24575
  int f = gid >> 6, l = gid & 63;            // f = 0..383
  int kt = f & 7, w = (f >> 3) & 3, g = (f >> 5) % 3, p = f / 96;
  int row = g * HH + p * 64 + w * 16 + (l & 15);
  int k0  = kt * 32 + (l >> 4) * 8;
  const float* src = srcW + (size_t)row * HH + k0;
  unsigned int o[4];
#pragma unroll
  for (int i = 0; i < 4; i++)
    o[i] = (unsigned int)f2bf(src[2 * i]) | ((unsigned int)f2bf(src[2 * i + 1]) << 16);
  *(uint4*)(dst + ((size_t)f * 64 + l) * 8) = *(uint4*)o;
}

// ---------------------------------------------------------------------------
// Fused split GRU scan (R13 = R12 with the poll fixed). 256 blocks x 256 thr,
// 1 block/CU by construction (LDS 82176B, launch_bounds(256,1), grid==#CU).
// R12 post-mortem: 256-thread ACQUIRE poll = per-iteration L2-invalidate
// storm (CDNA4 agent-acquire invalidates the XCD L2; L2s are not cross-XCD
// coherent) -> every load ~HBM latency -> 42us/step, MfmaUtil 0.8%.
// Fix: 4-thread RELAXED poll (agent-scope atomic loads bypass L2 via sc1 ->
// LLC-fresh with NO cache maintenance) + __syncthreads for ordering; and
// gi-MFMA moved BEFORE the poll so partner-release visibility lag hides
// under 466cy of X-side MFMA work.
// ---------------------------------------------------------------------------
__global__ __launch_bounds__(256, 1) void gru_scan(
    const float* __restrict__ tree, const float* __restrict__ seq,
    const int* __restrict__ mask,
    const unsigned short* __restrict__ wihf, const unsigned short* __restrict__ whhf,
    const float* __restrict__ bih, const float* __restrict__ bhh,
    unsigned short* __restrict__ hx, int* __restrict__ flags,
    float* __restrict__ out)
{
  __shared__ __align__(16) unsigned char lds[82176];
  unsigned short (*hbuf)[1088] = (unsigned short(*)[1088])lds;
  unsigned short (*xbuf)[1088] = (unsigned short(*)[1088])(lds + 4352);
  int* lsum = (int*)(lds + 8704);

  const int tid  = threadIdx.x;
  const int lane = tid & 63;
  const int w    = tid >> 6;          // wave = 16-dim tile within the part
  const int n16  = lane & 15;
  const int quad = lane >> 4;
  const int b    = n16 & 3;           // batch row owned by this lane
  const int rep  = n16 >> 2;          // replica (4 lanes duplicate work)
  const int p    = blockIdx.x >> 6;   // part: h-dims [p*64, p*64+64)
  const int bg   = blockIdx.x & 63;   // batch group
  const int brow0 = bg * 4;
  const int jbase = p * 64 + w * 16 + quad * 4;   // 4 owned h-dims

  if (tid < 4) lsum[tid] = 0;

  // lane-resident h (f32)
  f32x4 h4 = *(const f32x4*)(tree + (size_t)(brow0 + b) * HH + jbase);

  // stage FULL initial h into hbuf[0]: thread -> (batch tid>>6, dims (tid&63)*4)
  {
    int bi = tid >> 6, d0 = (tid & 63) * 4;
    f32x4 tv = *(const f32x4*)(tree + (size_t)(brow0 + bi) * HH + d0);
    unsigned int lo = (unsigned)f2bf(tv[0]) | ((unsigned)f2bf(tv[1]) << 16);
    unsigned int hi = (unsigned)f2bf(tv[2]) | ((unsigned)f2bf(tv[3]) << 16);
    int kt = d0 >> 5, q = (d0 >> 3) & 3;
    *(unsigned long long*)&hbuf[0][(kt * 17 + bi * 4 + q) * 8 + (d0 & 7)] =
        (unsigned long long)lo | ((unsigned long long)hi << 32);
  }
  // X staging: same (bi,d0) chunk; stage X(0); preload X(1) to regs
  const float* xgp = seq + ((size_t)(brow0 + (tid >> 6)) * HH + (tid & 63) * 4) * SSL;
  float xv0, xv1, xv2, xv3;
  {
    int bi = tid >> 6, d0 = (tid & 63) * 4;
    float a0 = xgp[0 * SSL], a1 = xgp[1 * SSL], a2 = xgp[2 * SSL], a3 = xgp[3 * SSL];
    unsigned int lo = (unsigned)f2bf(a0) | ((unsigned)f2bf(a1) << 16);
    unsigned int hi = (unsigned)f2bf(a2) | ((unsigned)f2bf(a3) << 16);
    int kt = d0 >> 5, q = (d0 >> 3) & 3;
    *(unsigned long long*)&xbuf[0][(kt * 17 + bi * 4 + q) * 8 + (d0 & 7)] =
        (unsigned long long)lo | ((unsigned long long)hi << 32);
    xv0 = xgp[0 * SSL + 1]; xv1 = xgp[1 * SSL + 1];
    xv2 = xgp[2 * SSL + 1]; xv3 = xgp[3 * SSL + 1];
  }
  {
    const int* mp = mask + (size_t)(brow0 + w) * SSL + lane * 8;
    int4 a = *(const int4*)mp;
    int4 c = *(const int4*)(mp + 4);
    atomicAdd(&lsum[w], a.x + a.y + a.z + a.w + c.x + c.y + c.z + c.w);
  }

  // W fragments: 3 gates x 8 kt each for Wih (VGPR) and Whh (AGPR)
  short8 awI[3][8], awH[3][8];
#pragma unroll
  for (int g = 0; g < 3; g++)
#pragma unroll
    for (int kt = 0; kt < 8; kt++) {
      size_t F = (size_t)(((p * 3 + g) * 4 + w) * 8 + kt) * 512;
      awI[g][kt] = *(const short8*)(wihf + F + (size_t)lane * 8);
      awH[g][kt] = *(const short8*)(whhf + F + (size_t)lane * 8);
    }
  // Pin (R5 lesson: without pins the allocator re-loads W from L2 every step)
#pragma unroll
  for (int g = 0; g < 3; g++)
#pragma unroll
    for (int kt = 0; kt < 8; kt++) {
      asm volatile("" : "+v"(awI[g][kt]));
      asm volatile("" : "+a"(awH[g][kt]));
    }

  // biases (f32, lane-resident): r/z combined, n split (torch GRUCell math)
  f32x4 brz = *(const f32x4*)(bih + jbase);
  f32x4 bzz = *(const f32x4*)(bih + HH + jbase);
  f32x4 bin = *(const f32x4*)(bih + 2 * HH + jbase);
  f32x4 bhn = *(const f32x4*)(bhh + 2 * HH + jbase);
  {
    f32x4 t0 = *(const f32x4*)(bhh + jbase);
    f32x4 t1 = *(const f32x4*)(bhh + HH + jbase);
#pragma unroll
    for (int e = 0; e < 4; e++) { brz[e] += t0[e]; bzz[e] += t1[e]; }
  }

  __syncthreads();
  int mylast = lsum[b] - 1; if (mylast < 0) mylast = 0;

  for (int t = 0; t < SSL; t++) {
    const int cb = t & 1, nb = cb ^ 1;

    // ---- xb fragments (X(t), staged last step) ----
    short8 xb[8];
    const unsigned short* xrp = &xbuf[cb][0] + (b * 4 + quad) * 8;
#pragma unroll
    for (int kt = 0; kt < 8; kt++)
      xb[kt] = *(const short8*)(xrp + kt * 136);

    // ---- gi-MFMAs FIRST: 466cy of X-side work hides partner-release lag ----
    f32x4 ri = f32x4{0.f, 0.f, 0.f, 0.f}, zi = ri, ni = ri;
#pragma unroll
    for (int kt = 0; kt < 8; kt++) {
      ri = __builtin_amdgcn_mfma_f32_16x16x32_bf16(awI[0][kt], xb[kt], ri, 0, 0, 0);
      zi = __builtin_amdgcn_mfma_f32_16x16x32_bf16(awI[1][kt], xb[kt], zi, 0, 0, 0);
      ni = __builtin_amdgcn_mfma_f32_16x16x32_bf16(awI[2][kt], xb[kt], ni, 0, 0, 0);
    }

    // ---- poll partners (4 threads, RELAXED — no cache maintenance) ----
    if (t > 0) {
      if (tid < 4) {
        const int* fl = flags + bg * 32 + tid;
        while (__hip_atomic_load(fl, __ATOMIC_RELAXED, __HIP_MEMORY_SCOPE_AGENT) < t) {}
      }
      __syncthreads();   // ordering: hx loads strictly after flag observation
      unsigned long long hv0 = 0, hv1 = 0;
      if (tid < 128) {
        int q4 = tid >> 5, bi = (tid >> 3) & 3, ch = tid & 7;
        const unsigned long long* s = (const unsigned long long*)
            (hx + (((size_t)nb * 64 + bg) * 4 + bi) * 256 + q4 * 64 + ch * 8);
        hv0 = __hip_atomic_load(s,     __ATOMIC_RELAXED, __HIP_MEMORY_SCOPE_AGENT);
        hv1 = __hip_atomic_load(s + 1, __ATOMIC_RELAXED, __HIP_MEMORY_SCOPE_AGENT);
        int d = q4 * 64 + ch * 8;
        int kt = d >> 5, qq = (d >> 3) & 3;
        unsigned long long* dst = (unsigned long long*)&hbuf[cb][(kt * 17 + bi * 4 + qq) * 8];
        dst[0] = hv0; dst[1] = hv1;
      }
      sync_lds();
    }

    // ---- gh-MFMAs: 3 chains x 8 ----
    short8 hb[8];
    const unsigned short* hrp = &hbuf[cb][0] + (b * 4 + quad) * 8;
#pragma unroll
    for (int kt = 0; kt < 8; kt++)
      hb[kt] = *(const short8*)(hrp + kt * 136);
    f32x4 rh = f32x4{0.f, 0.f, 0.f, 0.f}, zh = rh, nh = rh;
#pragma unroll
    for (int kt = 0; kt < 8; kt++) {
      rh = __builtin_amdgcn_mfma_f32_16x16x32_bf16(awH[0][kt], hb[kt], rh, 0, 0, 0);
      zh = __builtin_amdgcn_mfma_f32_16x16x32_bf16(awH[1][kt], hb[kt], zh, 0, 0, 0);
      nh = __builtin_amdgcn_mfma_f32_16x16x32_bf16(awH[2][kt], hb[kt], nh, 0, 0, 0);
    }

    // ---- gates in-register (wave owns its tile: no select) ----
#pragma unroll
    for (int e = 0; e < 4; e++) {
      float r = __builtin_amdgcn_rcpf(1.f + __expf(-(ri[e] + rh[e] + brz[e])));
      float z = __builtin_amdgcn_rcpf(1.f + __expf(-(zi[e] + zh[e] + bzz[e])));
      float a = ni[e] + bin[e] + r * (nh[e] + bhn[e]);
      float nn = 1.f - 2.f * __builtin_amdgcn_rcpf(__expf(2.f * a) + 1.f);
      h4[e] = nn + z * (h4[e] - nn);
    }

    // ---- post own slice h_t -> hx[cb] (agent atomics => LLC-visible) ----
    if (rep == 0) {
      unsigned int lo = (unsigned)f2bf(h4[0]) | ((unsigned)f2bf(h4[1]) << 16);
      unsigned int hi = (unsigned)f2bf(h4[2]) | ((unsigned)f2bf(h4[3]) << 16);
      unsigned long long u = (unsigned long long)lo | ((unsigned long long)hi << 32);
      __hip_atomic_store((unsigned long long*)
          (hx + (((size_t)cb * 64 + bg) * 4 + b) * 256 + jbase),
          u, __ATOMIC_RELAXED, __HIP_MEMORY_SCOPE_AGENT);
    }
    if (t == mylast)
      *(f32x4*)(out + (size_t)(brow0 + b) * HH + jbase) = h4;

    // every wave drains its own stores, then block joins, then tid0 releases
    asm volatile("s_waitcnt vmcnt(0)" ::: "memory");
    __syncthreads();
    if (tid == 0)
      __hip_atomic_store(flags + bg * 32 + p, t + 1,
                         __ATOMIC_RELEASE, __HIP_MEMORY_SCOPE_AGENT);

    // ---- stage xbuf[nb] <- X(t+1) (regs), then prefetch X(t+2) ----
    {
      int bi = tid >> 6, d0 = (tid & 63) * 4;
      unsigned int lo = (unsigned)f2bf(xv0) | ((unsigned)f2bf(xv1) << 16);
      unsigned int hi = (unsigned)f2bf(xv2) | ((unsigned)f2bf(xv3) << 16);
      int kt = d0 >> 5, q = (d0 >> 3) & 3;
      *(unsigned long long*)&xbuf[nb][(kt * 17 + bi * 4 + q) * 8 + (d0 & 7)] =
          (unsigned long long)lo | ((unsigned long long)hi << 32);
      int tn = (t + 2 < SSL) ? t + 2 : SSL - 1;
      xv0 = xgp[0 * SSL + tn]; xv1 = xgp[1 * SSL + tn];
      xv2 = xgp[2 * SSL + tn]; xv3 = xgp[3 * SSL + tn];
    }
    sync_lds();
  }
}

extern "C" void kernel_launch(void* const* d_in, const int* in_sizes, int n_in,
                              void* d_out, int out_size, void* d_ws, size_t ws_size,
                              hipStream_t stream) {
  const float* tree = (const float*)d_in[0];
  const float* seq  = (const float*)d_in[1];
  const int*   mask = (const int*)d_in[2];
  const float* Wih  = (const float*)d_in[3];
  const float* Whh  = (const float*)d_in[4];
  const float* bih  = (const float*)d_in[5];
  const float* bhh  = (const float*)d_in[6];
  float* out = (float*)d_out;

  unsigned short* hx    = (unsigned short*)d_ws;                    // 262,144 B
  int*            flags = (int*)((char*)d_ws + 262144);             //   8,192 B
  unsigned short* wihf  = (unsigned short*)((char*)d_ws + 270336);  // 393,216 B
  unsigned short* whhf  = (unsigned short*)((char*)d_ws + 663552);  // 393,216 B

  prep_pack<<<192, 256, 0, stream>>>(Wih, Whh, wihf, whhf, flags);
  gru_scan<<<256, 256, 0, stream>>>(tree, seq, mask, wihf, whhf,
                                    bih, bhh, hx, flags, out);
}

// Round 10
// 1218.058 us; speedup vs baseline: 17.5587x; 2.1516x over previous
//
#include <hip/hip_runtime.h>
#include <hip/hip_bf16.h>

#define HH 256
#define SSL 512

using short8 = __attribute__((ext_vector_type(8))) short;
using f32x4  = __attribute__((ext_vector_type(4))) float;

__device__ __forceinline__ unsigned short f2bf(float f) {
  unsigned int u = __float_as_uint(f);
  u += 0x7FFFu + ((u >> 16) & 1u);
  return (unsigned short)(u >> 16);
}
// lgkm drain + raw barrier + sched pin; vmcnt NOT drained (global loads stay in flight)
__device__ __forceinline__ void sync_lds() {
  asm volatile("s_waitcnt lgkmcnt(0)" ::: "memory");
  __builtin_amdgcn_s_barrier();
  __builtin_amdgcn_sched_barrier(0);
}

// ---------------------------------------------------------------------------
// Prep (R14): W_ih / W_hh -> bf16 MFMA-fragment images (same as R13):
// F(p,g,w,kt) = ((p*3+g)*4+w)*8+kt; row = g*256 + p*64 + w*16 + (l&15);
// k0 = kt*32 + (l>>4)*8. blocks 0..95 -> Wih, 96..191 -> Whh.
// Blocks 0..127 also zero the hx exchange buffer (versions start at 0).
// ---------------------------------------------------------------------------
__global__ __launch_bounds__(256) void prep_pack(
    const float* __restrict__ Wih, const float* __restrict__ Whh,
    unsigned short* __restrict__ wih_frag, unsigned short* __restrict__ whh_frag,
    unsigned long long* __restrict__ hx)
{
  int blk = blockIdx.x;
  if (blk < 128) {
    int gid = blk * 256 + threadIdx.x;   // 0..32767
    hx[gid * 2] = 0ull;
    hx[gid * 2 + 1] = 0ull;
  }
  const float* srcW = (blk < 96) ? Wih : Whh;
  unsigned short* dst = (blk < 96) ? wih_frag : whh_frag;
  int gid = (blk % 96) * 256 + threadIdx.x;  // 0..24575
  int f = gid >> 6, l = gid & 63;            // f = 0..383
  int kt = f & 7, w = (f >> 3) & 3, g = (f >> 5) % 3, p = f / 96;
  int row = g * HH + p * 64 + w * 16 + (l & 15);
  int k0  = kt * 32 + (l >> 4) * 8;
  const float* src = srcW + (size_t)row * HH + k0;
  unsigned int o[4];
#pragma unroll
  for (int i = 0; i < 4; i++)
    o[i] = (unsigned int)f2bf(src[2 * i]) | ((unsigned int)f2bf(src[2 * i + 1]) << 16);
  *(uint4*)(dst + ((size_t)f * 64 + l) * 8) = *(uint4*)o;
}

// ---------------------------------------------------------------------------
// Fused split GRU scan (R14). 256 blocks x 256 thr, 1 block/CU by
// construction (LDS 82176B, launch_bounds(256,1), grid == #CU).
// R13 post-mortem: 2-phase exchange = 5 serial LLC segments (store-ack
// drain ~2000cy + flag hop + poll + load + stage) ~4.3us/step. R14: flags
// DELETED; each hx word is self-contained [d1|d0|ver:u32] posted with a
// relaxed agent atomic (no drain, no ordering). Readers poll the data
// words directly (ver >= t), 192 thr x 2 words, unpack straight to hbuf.
// Parity double-buffer; observing ver=t+1 proves the partner consumed my
// ver=t generation => overwrite by ver=t+2 is race-free. Own slice goes
// regs->LDS (no LLC RT). Chain: post -> partner observes (~1-1.8us incl.
// visibility) -> stage.
// hx word index: hx[((par*64+bg)*4 + p)*4*32 + b*32 + w*8 + quad*2 + k2],
// dims jlocal = w*16 + quad*4 + 2*k2 + {0,1}; ver = t_writer + 1.
// ---------------------------------------------------------------------------
__global__ __launch_bounds__(256, 1) void gru_scan(
    const float* __restrict__ tree, const float* __restrict__ seq,
    const int* __restrict__ mask,
    const unsigned short* __restrict__ wihf, const unsigned short* __restrict__ whhf,
    const float* __restrict__ bih, const float* __restrict__ bhh,
    unsigned long long* __restrict__ hx, float* __restrict__ out)
{
  __shared__ __align__(16) unsigned char lds[82176];
  unsigned short (*hbuf)[1088] = (unsigned short(*)[1088])lds;
  unsigned short (*xbuf)[1088] = (unsigned short(*)[1088])(lds + 4352);
  int* lsum = (int*)(lds + 8704);

  const int tid  = threadIdx.x;
  const int lane = tid & 63;
  const int w    = tid >> 6;          // wave = 16-dim tile within the part
  const int n16  = lane & 15;
  const int quad = lane >> 4;
  const int b    = n16 & 3;           // batch row owned by this lane
  const int rep  = n16 >> 2;          // replica (4 lanes duplicate work)
  const int p    = blockIdx.x >> 6;   // part: h-dims [p*64, p*64+64)
  const int bg   = blockIdx.x & 63;   // batch group
  const int brow0 = bg * 4;
  const int jbase = p * 64 + w * 16 + quad * 4;   // 4 owned h-dims

  if (tid < 4) lsum[tid] = 0;

  // lane-resident h (f32)
  f32x4 h4 = *(const f32x4*)(tree + (size_t)(brow0 + b) * HH + jbase);

  // stage FULL initial h into hbuf[0]: thread -> (batch tid>>6, dims (tid&63)*4)
  {
    int bi = tid >> 6, d0 = (tid & 63) * 4;
    f32x4 tv = *(const f32x4*)(tree + (size_t)(brow0 + bi) * HH + d0);
    unsigned int lo = (unsigned)f2bf(tv[0]) | ((unsigned)f2bf(tv[1]) << 16);
    unsigned int hi = (unsigned)f2bf(tv[2]) | ((unsigned)f2bf(tv[3]) << 16);
    int kt = d0 >> 5, q = (d0 >> 3) & 3;
    *(unsigned long long*)&hbuf[0][(kt * 17 + bi * 4 + q) * 8 + (d0 & 7)] =
        (unsigned long long)lo | ((unsigned long long)hi << 32);
  }
  // X staging: same (bi,d0) chunk; stage X(0); preload X(1) to regs
  const float* xgp = seq + ((size_t)(brow0 + (tid >> 6)) * HH + (tid & 63) * 4) * SSL;
  float xv0, xv1, xv2, xv3;
  {
    int bi = tid >> 6, d0 = (tid & 63) * 4;
    float a0 = xgp[0 * SSL], a1 = xgp[1 * SSL], a2 = xgp[2 * SSL], a3 = xgp[3 * SSL];
    unsigned int lo = (unsigned)f2bf(a0) | ((unsigned)f2bf(a1) << 16);
    unsigned int hi = (unsigned)f2bf(a2) | ((unsigned)f2bf(a3) << 16);
    int kt = d0 >> 5, q = (d0 >> 3) & 3;
    *(unsigned long long*)&xbuf[0][(kt * 17 + bi * 4 + q) * 8 + (d0 & 7)] =
        (unsigned long long)lo | ((unsigned long long)hi << 32);
    xv0 = xgp[0 * SSL + 1]; xv1 = xgp[1 * SSL + 1];
    xv2 = xgp[2 * SSL + 1]; xv3 = xgp[3 * SSL + 1];
  }
  {
    const int* mp = mask + (size_t)(brow0 + w) * SSL + lane * 8;
    int4 a = *(const int4*)mp;
    int4 c = *(const int4*)(mp + 4);
    atomicAdd(&lsum[w], a.x + a.y + a.z + a.w + c.x + c.y + c.z + c.w);
  }

  // W fragments: 3 gates x 8 kt each for Wih (VGPR) and Whh (AGPR)
  short8 awI[3][8], awH[3][8];
#pragma unroll
  for (int g = 0; g < 3; g++)
#pragma unroll
    for (int kt = 0; kt < 8; kt++) {
      size_t F = (size_t)(((p * 3 + g) * 4 + w) * 8 + kt) * 512;
      awI[g][kt] = *(const short8*)(wihf + F + (size_t)lane * 8);
      awH[g][kt] = *(const short8*)(whhf + F + (size_t)lane * 8);
    }
  // Pin (R5 lesson: without pins the allocator re-loads W from L2 every step)
#pragma unroll
  for (int g = 0; g < 3; g++)
#pragma unroll
    for (int kt = 0; kt < 8; kt++) {
      asm volatile("" : "+v"(awI[g][kt]));
      asm volatile("" : "+a"(awH[g][kt]));
    }

  // biases (f32, lane-resident): r/z combined, n split (torch GRUCell math)
  f32x4 brz = *(const f32x4*)(bih + jbase);
  f32x4 bzz = *(const f32x4*)(bih + HH + jbase);
  f32x4 bin = *(const f32x4*)(bih + 2 * HH + jbase);
  f32x4 bhn = *(const f32x4*)(bhh + 2 * HH + jbase);
  {
    f32x4 t0 = *(const f32x4*)(bhh + jbase);
    f32x4 t1 = *(const f32x4*)(bhh + HH + jbase);
#pragma unroll
    for (int e = 0; e < 4; e++) { brz[e] += t0[e]; bzz[e] += t1[e]; }
  }

  // reader-side constants (tid < 192): which partner words this thread polls
  const int rpp  = tid / 64;               // 0..2
  const int rpart = rpp + (rpp >= p);      // partner part id (skip own)
  const int rbi  = (tid & 63) >> 4;        // batch row 0..3
  const int rww  = (tid & 15) * 2;         // word pair base 0..30
  const int rwq  = rww >> 3;               // partner wave 0..3
  const int rqd  = (rww >> 1) & 3;         // partner quad 0..3
  const int rd   = rpart * 64 + rwq * 16 + rqd * 4;   // 4 dims
  const int rslot = ((rd >> 5) * 17 + rbi * 4 + ((rd >> 3) & 3)) * 8 + (rd & 7);

  // writer-side (rep == 0): own 2 words
  unsigned long long* wdst = hx +
      ((((size_t)0 * 64 + bg) * 4 + p) * 4 + b) * 32 + (w * 8 + quad * 2);
  const size_t parstride = (size_t)64 * 4 * 4 * 32;   // words per parity
  // own-slice LDS slot (same formula, bi = b)
  const int oslot = ((jbase >> 5) * 17 + b * 4 + ((jbase >> 3) & 3)) * 8 + (jbase & 7);

  __syncthreads();
  int mylast = lsum[b] - 1; if (mylast < 0) mylast = 0;

  for (int t = 0; t < SSL; t++) {
    const int cb = t & 1, nb = cb ^ 1;

    // ---- xb fragments (X(t), staged last step) ----
    short8 xb[8];
    const unsigned short* xrp = &xbuf[cb][0] + (b * 4 + quad) * 8;
#pragma unroll
    for (int kt = 0; kt < 8; kt++)
      xb[kt] = *(const short8*)(xrp + kt * 136);

    // ---- gi-MFMAs FIRST: X-side work hides partner-post visibility lag ----
    f32x4 ri = f32x4{0.f, 0.f, 0.f, 0.f}, zi = ri, ni = ri;
#pragma unroll
    for (int kt = 0; kt < 8; kt++) {
      ri = __builtin_amdgcn_mfma_f32_16x16x32_bf16(awI[0][kt], xb[kt], ri, 0, 0, 0);
      zi = __builtin_amdgcn_mfma_f32_16x16x32_bf16(awI[1][kt], xb[kt], zi, 0, 0, 0);
      ni = __builtin_amdgcn_mfma_f32_16x16x32_bf16(awI[2][kt], xb[kt], ni, 0, 0, 0);
    }

    // ---- single-phase exchange read: poll versioned data words directly ----
    if (t > 0) {
      if (tid < 192) {
        const unsigned long long* src = hx + (size_t)nb * parstride +
            ((((size_t)bg) * 4 + rpart) * 4 + rbi) * 32 + rww;
        unsigned long long u0, u1;
        do { u0 = __hip_atomic_load(src, __ATOMIC_RELAXED, __HIP_MEMORY_SCOPE_AGENT);
        } while ((unsigned int)u0 < (unsigned int)t);
        do { u1 = __hip_atomic_load(src + 1, __ATOMIC_RELAXED, __HIP_MEMORY_SCOPE_AGENT);
        } while ((unsigned int)u1 < (unsigned int)t);
        *(unsigned int*)&hbuf[cb][rslot]     = (unsigned int)(u0 >> 32);  // dims rd, rd+1
        *(unsigned int*)&hbuf[cb][rslot + 2] = (unsigned int)(u1 >> 32);  // dims rd+2, rd+3
      }
      sync_lds();
    }

    // ---- gh-MFMAs: 3 chains x 8 ----
    short8 hb[8];
    const unsigned short* hrp = &hbuf[cb][0] + (b * 4 + quad) * 8;
#pragma unroll
    for (int kt = 0; kt < 8; kt++)
      hb[kt] = *(const short8*)(hrp + kt * 136);
    f32x4 rh = f32x4{0.f, 0.f, 0.f, 0.f}, zh = rh, nh = rh;
#pragma unroll
    for (int kt = 0; kt < 8; kt++) {
      rh = __builtin_amdgcn_mfma_f32_16x16x32_bf16(awH[0][kt], hb[kt], rh, 0, 0, 0);
      zh = __builtin_amdgcn_mfma_f32_16x16x32_bf16(awH[1][kt], hb[kt], zh, 0, 0, 0);
      nh = __builtin_amdgcn_mfma_f32_16x16x32_bf16(awH[2][kt], hb[kt], nh, 0, 0, 0);
    }

    // ---- gates in-register (wave owns its tile: no select) ----
#pragma unroll
    for (int e = 0; e < 4; e++) {
      float r = __builtin_amdgcn_rcpf(1.f + __expf(-(ri[e] + rh[e] + brz[e])));
      float z = __builtin_amdgcn_rcpf(1.f + __expf(-(zi[e] + zh[e] + bzz[e])));
      float a = ni[e] + bin[e] + r * (nh[e] + bhn[e]);
      float nn = 1.f - 2.f * __builtin_amdgcn_rcpf(__expf(2.f * a) + 1.f);
      h4[e] = nn + z * (h4[e] - nn);
    }

    // ---- post own slice: versioned words (NO drain, NO flag) + own->LDS ----
    {
      unsigned int lo = (unsigned)f2bf(h4[0]) | ((unsigned)f2bf(h4[1]) << 16);
      unsigned int hi = (unsigned)f2bf(h4[2]) | ((unsigned)f2bf(h4[3]) << 16);
      if (rep == 0) {
        unsigned long long w0 = ((unsigned long long)lo << 32) | (unsigned int)(t + 1);
        unsigned long long w1 = ((unsigned long long)hi << 32) | (unsigned int)(t + 1);
        unsigned long long* dst = wdst + (size_t)cb * parstride;
        __hip_atomic_store(dst,     w0, __ATOMIC_RELAXED, __HIP_MEMORY_SCOPE_AGENT);
        __hip_atomic_store(dst + 1, w1, __ATOMIC_RELAXED, __HIP_MEMORY_SCOPE_AGENT);
        // own slice for next step's gh (regs -> LDS, no LLC round-trip)
        *(unsigned int*)&hbuf[nb][oslot]     = lo;
        *(unsigned int*)&hbuf[nb][oslot + 2] = hi;
      }
    }
    if (t == mylast)
      *(f32x4*)(out + (size_t)(brow0 + b) * HH + jbase) = h4;

    // ---- stage xbuf[nb] <- X(t+1) (regs), then prefetch X(t+2) ----
    {
      int bi = tid >> 6, d0 = (tid & 63) * 4;
      unsigned int lo = (unsigned)f2bf(xv0) | ((unsigned)f2bf(xv1) << 16);
      unsigned int hi = (unsigned)f2bf(xv2) | ((unsigned)f2bf(xv3) << 16);
      int kt = d0 >> 5, q = (d0 >> 3) & 3;
      *(unsigned long long*)&xbuf[nb][(kt * 17 + bi * 4 + q) * 8 + (d0 & 7)] =
          (unsigned long long)lo | ((unsigned long long)hi << 32);
      int tn = (t + 2 < SSL) ? t + 2 : SSL - 1;
      xv0 = xgp[0 * SSL + tn]; xv1 = xgp[1 * SSL + tn];
      xv2 = xgp[2 * SSL + tn]; xv3 = xgp[3 * SSL + tn];
    }
    sync_lds();
  }
}

extern "C" void kernel_launch(void* const* d_in, const int* in_sizes, int n_in,
                              void* d_out, int out_size, void* d_ws, size_t ws_size,
                              hipStream_t stream) {
  const float* tree = (const float*)d_in[0];
  const float* seq  = (const float*)d_in[1];
  const int*   mask = (const int*)d_in[2];
  const float* Wih  = (const float*)d_in[3];
  const float* Whh  = (const float*)d_in[4];
  const float* bih  = (const float*)d_in[5];
  const float* bhh  = (const float*)d_in[6];
  float* out = (float*)d_out;

  unsigned long long* hx = (unsigned long long*)d_ws;               // 524,288 B
  unsigned short* wihf  = (unsigned short*)((char*)d_ws + 524288);  // 393,216 B
  unsigned short* whhf  = (unsigned short*)((char*)d_ws + 917504);  // 393,216 B

  prep_pack<<<192, 256, 0, stream>>>(Wih, Whh, wihf, whhf, hx);
  gru_scan<<<256, 256, 0, stream>>>(tree, seq, mask, wihf, whhf,
                                    bih, bhh, hx, out);
}